// Round 1
// baseline (283.794 us; speedup 1.0000x reference)
//
#include <hip/hip_runtime.h>

// GridPoolingLayer: per-cell mean pooling where cells are rectangles defined
// by rising edges of h_mask (rows) and v_mask (cols). H=W=768, C=64, fp32.
//
// R3: split reduce / broadcast + 4-way MLP gather.
//   cell_mean : one WAVE per cell, 4 independent flat-index "walkers" per lane
//               so 4 loads are in flight every iteration (avg 16-px cell =>
//               whole cell read in ONE memory round-trip). Writes only the
//               256 B mean per cell (means buffer in d_ws).
//   bcast     : pure streaming writes, 4 KB dense per wave-instruction
//               regardless of cell geometry. Means reads are L2/L3-resident.
//   Fallback (ws too small): means stored at each cell's anchor pixel in out;
//   broadcast reads anchors (same-value race on anchors is benign).

#define GH 768
#define GW 768
#define MAXSEG 385  // alternating mask gives 384 rising edges -> 385 segments

enum {
    OFF_ROWSTART = 0,
    OFF_ROWEND   = OFF_ROWSTART + MAXSEG,
    OFF_COLSTART = OFF_ROWEND + MAXSEG,
    OFF_COLEND   = OFF_COLSTART + MAXSEG,
    OFF_NROWS    = OFF_COLEND + MAXSEG,
    OFF_NCOLS    = OFF_NROWS + 1,
    OFF_ROWID    = OFF_NCOLS + 1,        // [GH]  row-segment id per y
    OFF_COLID    = OFF_ROWID + GH,       // [GW]  col-segment id per x
    OFF_MEANS    = 4096,                 // float4 means[cell][16], 16B-aligned
};

__global__ __launch_bounds__(768) void seg_scan(const int* __restrict__ h_mask,
                                                const int* __restrict__ v_mask,
                                                int* __restrict__ ws) {
    __shared__ int s[GH];
    const int i = threadIdx.x;
    const bool is_row = (blockIdx.x == 0);
    const int* m = is_row ? h_mask : v_mask;

    int mi = m[i];
    int rising = 0;
    if (i > 0) rising = (mi == 1 && m[i - 1] == 0) ? 1 : 0;  // rising[0] forced 0
    s[i] = rising;
    __syncthreads();

    for (int off = 1; off < GH; off <<= 1) {
        int add = (i >= off) ? s[i - off] : 0;
        __syncthreads();
        s[i] += add;
        __syncthreads();
    }

    const int seg  = s[i];
    const int segL = (i == 0)      ? -1 : s[i - 1];
    const int segR = (i == GH - 1) ? -2 : s[i + 1];

    ws[(is_row ? OFF_ROWID : OFF_COLID) + i] = seg;   // per-pixel segment id

    int* start = ws + (is_row ? OFF_ROWSTART : OFF_COLSTART);
    int* end   = ws + (is_row ? OFF_ROWEND   : OFF_COLEND);
    if (seg != segL) start[seg] = i;
    if (seg != segR) end[seg]   = i + 1;
    if (i == GH - 1) ws[is_row ? OFF_NROWS : OFF_NCOLS] = seg + 1;
}

// One wave per cell (stride over cells). Lane = pg*16 + cq.
// Flat pixel order within the cell: f in [0,npx), y = y0+f/w, x = x0+f%w.
// Lane pg owns f ≡ pg (mod 4); walker k starts at f = pg+4k and steps +16.
// anchor_mode==0: mean -> dst[cell*16 + cq]   (dst = means region of ws)
// anchor_mode==1: mean -> dst[(y0*GW+x0)*16 + cq]  (dst = out, anchor pixel)
__global__ __launch_bounds__(256) void cell_mean(const float4* __restrict__ in,
                                                 float4* __restrict__ dst,
                                                 const int* __restrict__ ws,
                                                 int anchor_mode) {
    const int nrows  = ws[OFF_NROWS];
    const int ncols  = ws[OFF_NCOLS];
    const int ncells = nrows * ncols;

    const int wave   = blockIdx.x * 4 + (threadIdx.x >> 6);
    const int nwaves = gridDim.x * 4;
    const int lane   = threadIdx.x & 63;
    const int pg     = lane >> 4;   // pixel-residue group (f mod 4)
    const int cq     = lane & 15;   // channel quad: floats 4*cq .. 4*cq+3

    for (int cell = wave; cell < ncells; cell += nwaves) {
        const int br = cell / ncols;
        const int bc = cell - br * ncols;
        const int y0 = ws[OFF_ROWSTART + br];
        const int y1 = ws[OFF_ROWEND + br];
        const int x0 = ws[OFF_COLSTART + bc];
        const int x1 = ws[OFF_COLEND + bc];
        const int w   = x1 - x0;            // >= 1
        const int npx = w * (y1 - y0);      // >= 1
        const int q16 = 16 / w;             // per-cell, wave-uniform
        const int r16 = 16 - q16 * w;       // 16 % w  (< w)

        int wy[4], wx[4];
        #pragma unroll
        for (int k = 0; k < 4; ++k) {       // init walker at f = pg + 4k
            int t  = x0 + pg + 4 * k;
            int yy = y0;
            while (t >= x1) { t -= w; ++yy; }  // <= 15 iters (f0 <= 15)
            wx[k] = t; wy[k] = yy;
        }

        float4 a0 = make_float4(0.f, 0.f, 0.f, 0.f);
        float4 a1 = a0, a2 = a0, a3 = a0;

        const int nit = (npx + 15) >> 4;
        for (int it = 0; it < nit; ++it) {
            // 4 independent guarded loads -> 4 requests in flight per lane
            if (wy[0] < y1) { float4 v = in[(wy[0] * GW + wx[0]) * 16 + cq];
                a0.x += v.x; a0.y += v.y; a0.z += v.z; a0.w += v.w; }
            if (wy[1] < y1) { float4 v = in[(wy[1] * GW + wx[1]) * 16 + cq];
                a1.x += v.x; a1.y += v.y; a1.z += v.z; a1.w += v.w; }
            if (wy[2] < y1) { float4 v = in[(wy[2] * GW + wx[2]) * 16 + cq];
                a2.x += v.x; a2.y += v.y; a2.z += v.z; a2.w += v.w; }
            if (wy[3] < y1) { float4 v = in[(wy[3] * GW + wx[3]) * 16 + cq];
                a3.x += v.x; a3.y += v.y; a3.z += v.z; a3.w += v.w; }
            #pragma unroll
            for (int k = 0; k < 4; ++k) {   // step +16 in flat space
                wx[k] += r16; wy[k] += q16;
                if (wx[k] >= x1) { wx[k] -= w; wy[k] += 1; }
            }
        }

        float4 acc;
        acc.x = (a0.x + a1.x) + (a2.x + a3.x);
        acc.y = (a0.y + a1.y) + (a2.y + a3.y);
        acc.z = (a0.z + a1.z) + (a2.z + a3.z);
        acc.w = (a0.w + a1.w) + (a2.w + a3.w);
        #pragma unroll
        for (int msk = 16; msk < 64; msk <<= 1) {   // combine the 4 pg groups
            acc.x += __shfl_xor(acc.x, msk, 64);
            acc.y += __shfl_xor(acc.y, msk, 64);
            acc.z += __shfl_xor(acc.z, msk, 64);
            acc.w += __shfl_xor(acc.w, msk, 64);
        }

        if (lane < 16) {
            const float inv = 1.f / (float)npx;
            float4 mean = make_float4(acc.x * inv, acc.y * inv,
                                      acc.z * inv, acc.w * inv);
            const int oidx = anchor_mode ? (y0 * GW + x0) * 16 + lane
                                         : cell * 16 + lane;
            dst[oidx] = mean;
        }
    }
}

// Dense streaming broadcast, means from ws: loads and stores go through
// provably-distinct pointers so iterations pipeline freely.
// Grid MUST be 2048x256: 768*768*16 float4 / (2048*256) = exactly 18 per thread.
__global__ __launch_bounds__(256) void bcast_ws(float4* __restrict__ out,
                                                const float4* __restrict__ means,
                                                const int* __restrict__ ws) {
    const int ncols = ws[OFF_NCOLS];
    int g = blockIdx.x * 256 + threadIdx.x;
    #pragma unroll 3
    for (int it = 0; it < 18; ++it, g += 2048 * 256) {
        const int p  = g >> 4;
        const int cq = g & 15;
        const int y  = p / GW;              // constant divisor -> magic mul
        const int x  = p - y * GW;
        const int rid = ws[OFF_ROWID + y];
        const int cid = ws[OFF_COLID + x];
        out[g] = means[(rid * ncols + cid) * 16 + cq];
    }
}

// Fallback broadcast: means live at each cell's anchor pixel inside out.
// Reads/writes alias through `out` (conservative ordering) — correct, slower.
__global__ __launch_bounds__(256) void bcast_anchor(float4* out,
                                                    const int* __restrict__ ws) {
    int g = blockIdx.x * 256 + threadIdx.x;
    for (int it = 0; it < 18; ++it, g += 2048 * 256) {
        const int p  = g >> 4;
        const int cq = g & 15;
        const int y  = p / GW;
        const int x  = p - y * GW;
        const int rid = ws[OFF_ROWID + y];
        const int cid = ws[OFF_COLID + x];
        const int ya  = ws[OFF_ROWSTART + rid];
        const int xa  = ws[OFF_COLSTART + cid];
        out[g] = out[(ya * GW + xa) * 16 + cq];   // anchor holds the mean
    }
}

extern "C" void kernel_launch(void* const* d_in, const int* in_sizes, int n_in,
                              void* d_out, int out_size, void* d_ws, size_t ws_size,
                              hipStream_t stream) {
    const float* in  = (const float*)d_in[0];   // [1,768,768,64] fp32
    const int* hmask = (const int*)d_in[1];     // [1,768] int32
    const int* vmask = (const int*)d_in[2];     // [1,768] int32
    float* out = (float*)d_out;                 // [1,768,768,64] fp32
    int* ws = (int*)d_ws;

    seg_scan<<<2, GH, 0, stream>>>(hmask, vmask, ws);

    // means buffer: worst case MAXSEG*MAXSEG cells x 64 ch x 4 B
    const size_t need = (size_t)OFF_MEANS * 4
                      + (size_t)MAXSEG * MAXSEG * 64 * 4;
    if (ws_size >= need) {
        float4* means = (float4*)(ws + OFF_MEANS);
        cell_mean<<<2048, 256, 0, stream>>>((const float4*)in, means, ws, 0);
        bcast_ws<<<2048, 256, 0, stream>>>((float4*)out, means, ws);
    } else {
        cell_mean<<<2048, 256, 0, stream>>>((const float4*)in, (float4*)out, ws, 1);
        bcast_anchor<<<2048, 256, 0, stream>>>((float4*)out, ws);
    }
}

// Round 5
// 277.549 us; speedup vs baseline: 1.0225x; 1.0225x over previous
//
#include <hip/hip_runtime.h>

// GridPoolingLayer: per-cell mean pooling where cells are rectangles defined
// by rising edges of h_mask (rows) and v_mask (cols). H=W=768, C=64, fp32.
//
// R4 (4th attempt; three prior benches died on container acquisition — infra,
// not kernel: same launch structure as the R3 kernel that ran fine in R1):
//   cell_mean2: one WAVE per cell. Each 16-lane channel group (pg=0..3) owns a
//     CONTIGUOUS quarter of the cell's flat pixel range -> every iteration
//     issues 4 consecutive-pixel loads (1 KB contiguous per group) with NO
//     branches: addresses are clamped (min(y, y1-1)), values masked by
//     (j < len). All 4 loads sit in one basic block -> one waitcnt, 4
//     requests in flight. Walker init = one integer division (no serial
//     while loop). Mean written compactly to ws (256 B/cell).
//   bcast_ws: dense streaming broadcast (4 KB/wave-instr), means L2-resident.
//   Fallback (ws too small): means at cell anchor pixel in out + bcast_anchor.

#define GH 768
#define GW 768
#define MAXSEG 385  // alternating mask gives 384 rising edges -> 385 segments

enum {
    OFF_ROWSTART = 0,
    OFF_ROWEND   = OFF_ROWSTART + MAXSEG,
    OFF_COLSTART = OFF_ROWEND + MAXSEG,
    OFF_COLEND   = OFF_COLSTART + MAXSEG,
    OFF_NROWS    = OFF_COLEND + MAXSEG,
    OFF_NCOLS    = OFF_NROWS + 1,
    OFF_ROWID    = OFF_NCOLS + 1,        // [GH]  row-segment id per y
    OFF_COLID    = OFF_ROWID + GH,       // [GW]  col-segment id per x
    OFF_MEANS    = 4096,                 // float4 means[cell][16], 16B-aligned
};

__global__ __launch_bounds__(768) void seg_scan(const int* __restrict__ h_mask,
                                                const int* __restrict__ v_mask,
                                                int* __restrict__ ws) {
    __shared__ int s[GH];
    const int i = threadIdx.x;
    const bool is_row = (blockIdx.x == 0);
    const int* m = is_row ? h_mask : v_mask;

    int mi = m[i];
    int rising = 0;
    if (i > 0) rising = (mi == 1 && m[i - 1] == 0) ? 1 : 0;  // rising[0] forced 0
    s[i] = rising;
    __syncthreads();

    for (int off = 1; off < GH; off <<= 1) {
        int add = (i >= off) ? s[i - off] : 0;
        __syncthreads();
        s[i] += add;
        __syncthreads();
    }

    const int seg  = s[i];
    const int segL = (i == 0)      ? -1 : s[i - 1];
    const int segR = (i == GH - 1) ? -2 : s[i + 1];

    ws[(is_row ? OFF_ROWID : OFF_COLID) + i] = seg;   // per-pixel segment id

    int* start = ws + (is_row ? OFF_ROWSTART : OFF_COLSTART);
    int* end   = ws + (is_row ? OFF_ROWEND   : OFF_COLEND);
    if (seg != segL) start[seg] = i;
    if (seg != segR) end[seg]   = i + 1;
    if (i == GH - 1) ws[is_row ? OFF_NROWS : OFF_NCOLS] = seg + 1;
}

// One wave per cell (stride over cells). lane = pg*16 + cq.
// Flat pixel order within the cell: f in [0,npx), y = y0+f/w, x = x0+f%w.
// Group pg owns flat range [pg*q, min((pg+1)*q, npx)), q = ceil(npx/4):
// contiguous pixels -> 4 consecutive 256B loads per iteration, no branches.
// anchor_mode==0: mean -> dst[cell*16 + cq]       (dst = means region of ws)
// anchor_mode==1: mean -> dst[(y0*GW+x0)*16 + cq] (dst = out, anchor pixel)
__global__ __launch_bounds__(256) void cell_mean2(const float4* __restrict__ in,
                                                  float4* __restrict__ dst,
                                                  const int* __restrict__ ws,
                                                  int anchor_mode) {
    const int nrows  = ws[OFF_NROWS];
    const int ncols  = ws[OFF_NCOLS];
    const int ncells = nrows * ncols;

    const int wave   = blockIdx.x * 4 + (threadIdx.x >> 6);
    const int nwaves = gridDim.x * 4;
    const int lane   = threadIdx.x & 63;
    const int pg     = lane >> 4;   // quarter-of-cell group
    const int cq     = lane & 15;   // channel quad: floats 4*cq .. 4*cq+3

    for (int cell = wave; cell < ncells; cell += nwaves) {
        const int br = cell / ncols;
        const int bc = cell - br * ncols;
        const int y0 = ws[OFF_ROWSTART + br];
        const int y1 = ws[OFF_ROWEND + br];
        const int x0 = ws[OFF_COLSTART + bc];
        const int x1 = ws[OFF_COLEND + bc];
        const int w    = x1 - x0;           // >= 1
        const int npx  = w * (y1 - y0);     // >= 1
        const int q    = (npx + 3) >> 2;    // quarter size
        const int base = pg * q;
        const int endf = min(base + q, npx);
        int len = endf - base;              // may be <= 0 for tiny cells
        const int ylim = y1 - 1;

        // walker init at flat index 'base' via one integer division
        const unsigned ub = (unsigned)base;
        const unsigned uy = ub / (unsigned)w;
        int yy = y0 + (int)uy;
        int xx = x0 + (int)(ub - uy * (unsigned)w);

        float4 acc = make_float4(0.f, 0.f, 0.f, 0.f);

        while (len > 0) {
            // 4 consecutive flat pixels; chained wrap (each step wraps <= once)
            const int xA = xx;           const int yAc = min(yy, ylim);
            int xB = xx + 1, yB = yy;  if (xB >= x1) { xB = x0; ++yB; }
            const int yBc = min(yB, ylim);
            int xC = xB + 1, yC = yB;  if (xC >= x1) { xC = x0; ++yC; }
            const int yCc = min(yC, ylim);
            int xD = xC + 1, yD = yC;  if (xD >= x1) { xD = x0; ++yD; }
            const int yDc = min(yD, ylim);

            // all 4 loads in one BB -> batched, single waitcnt region
            const float4 vA = in[(yAc * GW + xA) * 16 + cq];
            const float4 vB = in[(yBc * GW + xB) * 16 + cq];
            const float4 vC = in[(yCc * GW + xC) * 16 + cq];
            const float4 vD = in[(yDc * GW + xD) * 16 + cq];

            const bool mB = (1 < len), mC = (2 < len), mD = (3 < len);
            acc.x += vA.x;  acc.y += vA.y;  acc.z += vA.z;  acc.w += vA.w;
            acc.x += mB ? vB.x : 0.f;  acc.y += mB ? vB.y : 0.f;
            acc.z += mB ? vB.z : 0.f;  acc.w += mB ? vB.w : 0.f;
            acc.x += mC ? vC.x : 0.f;  acc.y += mC ? vC.y : 0.f;
            acc.z += mC ? vC.z : 0.f;  acc.w += mC ? vC.w : 0.f;
            acc.x += mD ? vD.x : 0.f;  acc.y += mD ? vD.y : 0.f;
            acc.z += mD ? vD.z : 0.f;  acc.w += mD ? vD.w : 0.f;

            // advance to next 4 pixels
            int xE = xD + 1, yE = yD;  if (xE >= x1) { xE = x0; ++yE; }
            xx = xE; yy = yE;
            len -= 4;
        }

        // combine the 4 quarter-sums; all lanes end with the full sum
        #pragma unroll
        for (int msk = 16; msk < 64; msk <<= 1) {
            acc.x += __shfl_xor(acc.x, msk, 64);
            acc.y += __shfl_xor(acc.y, msk, 64);
            acc.z += __shfl_xor(acc.z, msk, 64);
            acc.w += __shfl_xor(acc.w, msk, 64);
        }

        if (lane < 16) {
            const float inv = 1.f / (float)npx;
            float4 mean = make_float4(acc.x * inv, acc.y * inv,
                                      acc.z * inv, acc.w * inv);
            const int oidx = anchor_mode ? (y0 * GW + x0) * 16 + lane
                                         : cell * 16 + lane;
            dst[oidx] = mean;
        }
    }
}

// Dense streaming broadcast, means from ws: loads and stores go through
// provably-distinct pointers so iterations pipeline freely.
// Grid MUST be 2048x256: 768*768*16 float4 / (2048*256) = exactly 18 per thread.
__global__ __launch_bounds__(256) void bcast_ws(float4* __restrict__ out,
                                                const float4* __restrict__ means,
                                                const int* __restrict__ ws) {
    const int ncols = ws[OFF_NCOLS];
    int g = blockIdx.x * 256 + threadIdx.x;
    #pragma unroll 3
    for (int it = 0; it < 18; ++it, g += 2048 * 256) {
        const int p  = g >> 4;
        const int cq = g & 15;
        const int y  = p / GW;              // constant divisor -> magic mul
        const int x  = p - y * GW;
        const int rid = ws[OFF_ROWID + y];
        const int cid = ws[OFF_COLID + x];
        out[g] = means[(rid * ncols + cid) * 16 + cq];
    }
}

// Fallback broadcast: means live at each cell's anchor pixel inside out.
// Reads/writes alias through `out` (conservative ordering) — correct, slower.
__global__ __launch_bounds__(256) void bcast_anchor(float4* out,
                                                    const int* __restrict__ ws) {
    int g = blockIdx.x * 256 + threadIdx.x;
    for (int it = 0; it < 18; ++it, g += 2048 * 256) {
        const int p  = g >> 4;
        const int cq = g & 15;
        const int y  = p / GW;
        const int x  = p - y * GW;
        const int rid = ws[OFF_ROWID + y];
        const int cid = ws[OFF_COLID + x];
        const int ya  = ws[OFF_ROWSTART + rid];
        const int xa  = ws[OFF_COLSTART + cid];
        out[g] = out[(ya * GW + xa) * 16 + cq];   // anchor holds the mean
    }
}

extern "C" void kernel_launch(void* const* d_in, const int* in_sizes, int n_in,
                              void* d_out, int out_size, void* d_ws, size_t ws_size,
                              hipStream_t stream) {
    const float* in  = (const float*)d_in[0];   // [1,768,768,64] fp32
    const int* hmask = (const int*)d_in[1];     // [1,768] int32
    const int* vmask = (const int*)d_in[2];     // [1,768] int32
    float* out = (float*)d_out;                 // [1,768,768,64] fp32
    int* ws = (int*)d_ws;

    seg_scan<<<2, GH, 0, stream>>>(hmask, vmask, ws);

    // means buffer: worst case MAXSEG*MAXSEG cells x 64 ch x 4 B
    const size_t need = (size_t)OFF_MEANS * 4
                      + (size_t)MAXSEG * MAXSEG * 64 * 4;
    if (ws_size >= need) {
        float4* means = (float4*)(ws + OFF_MEANS);
        cell_mean2<<<2048, 256, 0, stream>>>((const float4*)in, means, ws, 0);
        bcast_ws<<<2048, 256, 0, stream>>>((float4*)out, means, ws);
    } else {
        cell_mean2<<<2048, 256, 0, stream>>>((const float4*)in, (float4*)out, ws, 1);
        bcast_anchor<<<2048, 256, 0, stream>>>((float4*)out, ws);
    }
}

// Round 7
// 271.336 us; speedup vs baseline: 1.0459x; 1.0229x over previous
//
#include <hip/hip_runtime.h>

// GridPoolingLayer: per-cell mean pooling where cells are rectangles defined
// by rising edges of h_mask (rows) and v_mask (cols). H=W=768, C=64, fp32.
//
// R5 (2nd attempt; prior bench died on container acquisition — infra):
//   cell_mean3: one WAVE per cell; each 16-lane channel group owns a
//     contiguous quarter of the cell's flat pixel range (branch-free clamped
//     loads, masked adds — from R4). NEW: the NEXT cell's 4 descriptor loads
//     are issued BEFORE the current cell's gather, so the L2 descriptor
//     round-trip hides under the HBM gather round-trip (vmcnt retires in
//     issue order; descriptors complete first). Cuts the per-cell serial
//     chain by the descriptor latency (~30%).
//   bcast_ws: dense streaming broadcast; out stores are NONTEMPORAL (147 MB
//     write-once — avoid L2 write-allocate pollution); unroll 6 for more
//     outstanding means loads.
//   Fallback (ws too small): means at cell anchor pixel in out + bcast_anchor.

#define GH 768
#define GW 768
#define MAXSEG 385  // alternating mask gives 384 rising edges -> 385 segments

typedef __attribute__((ext_vector_type(4))) float f32x4;

enum {
    OFF_ROWSTART = 0,
    OFF_ROWEND   = OFF_ROWSTART + MAXSEG,
    OFF_COLSTART = OFF_ROWEND + MAXSEG,
    OFF_COLEND   = OFF_COLSTART + MAXSEG,
    OFF_NROWS    = OFF_COLEND + MAXSEG,
    OFF_NCOLS    = OFF_NROWS + 1,
    OFF_ROWID    = OFF_NCOLS + 1,        // [GH]  row-segment id per y
    OFF_COLID    = OFF_ROWID + GH,       // [GW]  col-segment id per x
    OFF_MEANS    = 4096,                 // float4 means[cell][16], 16B-aligned
};

__global__ __launch_bounds__(768) void seg_scan(const int* __restrict__ h_mask,
                                                const int* __restrict__ v_mask,
                                                int* __restrict__ ws) {
    __shared__ int s[GH];
    const int i = threadIdx.x;
    const bool is_row = (blockIdx.x == 0);
    const int* m = is_row ? h_mask : v_mask;

    int mi = m[i];
    int rising = 0;
    if (i > 0) rising = (mi == 1 && m[i - 1] == 0) ? 1 : 0;  // rising[0] forced 0
    s[i] = rising;
    __syncthreads();

    for (int off = 1; off < GH; off <<= 1) {
        int add = (i >= off) ? s[i - off] : 0;
        __syncthreads();
        s[i] += add;
        __syncthreads();
    }

    const int seg  = s[i];
    const int segL = (i == 0)      ? -1 : s[i - 1];
    const int segR = (i == GH - 1) ? -2 : s[i + 1];

    ws[(is_row ? OFF_ROWID : OFF_COLID) + i] = seg;   // per-pixel segment id

    int* start = ws + (is_row ? OFF_ROWSTART : OFF_COLSTART);
    int* end   = ws + (is_row ? OFF_ROWEND   : OFF_COLEND);
    if (seg != segL) start[seg] = i;
    if (seg != segR) end[seg]   = i + 1;
    if (i == GH - 1) ws[is_row ? OFF_NROWS : OFF_NCOLS] = seg + 1;
}

// One wave per cell (stride over cells). lane = pg*16 + cq.
// Flat pixel order within the cell: f in [0,npx), y = y0+f/w, x = x0+f%w.
// Group pg owns flat range [pg*q, min((pg+1)*q, npx)), q = ceil(npx/4).
// anchor_mode==0: mean -> dst[cell*16 + cq]       (dst = means region of ws)
// anchor_mode==1: mean -> dst[(y0*GW+x0)*16 + cq] (dst = out, anchor pixel)
__global__ __launch_bounds__(256) void cell_mean3(const float4* __restrict__ in,
                                                  float4* __restrict__ dst,
                                                  const int* __restrict__ ws,
                                                  int anchor_mode) {
    const int nrows  = ws[OFF_NROWS];
    const int ncols  = ws[OFF_NCOLS];
    const int ncells = nrows * ncols;

    const int wave   = blockIdx.x * 4 + (threadIdx.x >> 6);
    const int nwaves = gridDim.x * 4;
    const int lane   = threadIdx.x & 63;
    const int pg     = lane >> 4;   // quarter-of-cell group
    const int cq     = lane & 15;   // channel quad: floats 4*cq .. 4*cq+3

    int cell = wave;
    if (cell >= ncells) return;

    // descriptors for the first cell (not overlapped; happens once)
    int br = cell / ncols;
    int bc = cell - br * ncols;
    int y0 = ws[OFF_ROWSTART + br];
    int y1 = ws[OFF_ROWEND   + br];
    int x0 = ws[OFF_COLSTART + bc];
    int x1 = ws[OFF_COLEND   + bc];

    while (true) {
        // ---- prefetch NEXT cell's descriptors: issued before the gather so
        // their L2 latency hides under the gather's HBM latency ----
        const int ncell     = cell + nwaves;
        const bool have_next = (ncell < ncells);
        const int cc  = have_next ? ncell : 0;      // clamped safe index
        const int nbr = cc / ncols;
        const int nbc = cc - nbr * ncols;
        const int ny0 = ws[OFF_ROWSTART + nbr];
        const int ny1 = ws[OFF_ROWEND   + nbr];
        const int nx0 = ws[OFF_COLSTART + nbc];
        const int nx1 = ws[OFF_COLEND   + nbc];

        // ---- gather current cell ----
        const int w    = x1 - x0;           // >= 1
        const int npx  = w * (y1 - y0);     // >= 1
        const int q    = (npx + 3) >> 2;    // quarter size
        const int base = pg * q;
        int len = min(base + q, npx) - base;  // may be <= 0 for tiny cells
        const int ylim = y1 - 1;

        // walker init at flat index 'base' via one integer division
        const unsigned ub = (unsigned)base;
        const unsigned uy = ub / (unsigned)w;
        int yy = y0 + (int)uy;
        int xx = x0 + (int)(ub - uy * (unsigned)w);

        float4 acc = make_float4(0.f, 0.f, 0.f, 0.f);

        while (len > 0) {
            // 4 consecutive flat pixels; chained wrap (each step wraps <= once)
            const int xA = xx;           const int yAc = min(yy, ylim);
            int xB = xx + 1, yB = yy;  if (xB >= x1) { xB = x0; ++yB; }
            const int yBc = min(yB, ylim);
            int xC = xB + 1, yC = yB;  if (xC >= x1) { xC = x0; ++yC; }
            const int yCc = min(yC, ylim);
            int xD = xC + 1, yD = yC;  if (xD >= x1) { xD = x0; ++yD; }
            const int yDc = min(yD, ylim);

            // all 4 loads in one BB -> batched, single waitcnt region
            const float4 vA = in[(yAc * GW + xA) * 16 + cq];
            const float4 vB = in[(yBc * GW + xB) * 16 + cq];
            const float4 vC = in[(yCc * GW + xC) * 16 + cq];
            const float4 vD = in[(yDc * GW + xD) * 16 + cq];

            const bool mB = (1 < len), mC = (2 < len), mD = (3 < len);
            acc.x += vA.x;  acc.y += vA.y;  acc.z += vA.z;  acc.w += vA.w;
            acc.x += mB ? vB.x : 0.f;  acc.y += mB ? vB.y : 0.f;
            acc.z += mB ? vB.z : 0.f;  acc.w += mB ? vB.w : 0.f;
            acc.x += mC ? vC.x : 0.f;  acc.y += mC ? vC.y : 0.f;
            acc.z += mC ? vC.z : 0.f;  acc.w += mC ? vC.w : 0.f;
            acc.x += mD ? vD.x : 0.f;  acc.y += mD ? vD.y : 0.f;
            acc.z += mD ? vD.z : 0.f;  acc.w += mD ? vD.w : 0.f;

            // advance to next 4 pixels
            int xE = xD + 1, yE = yD;  if (xE >= x1) { xE = x0; ++yE; }
            xx = xE; yy = yE;
            len -= 4;
        }

        // combine the 4 quarter-sums; all lanes end with the full sum
        #pragma unroll
        for (int msk = 16; msk < 64; msk <<= 1) {
            acc.x += __shfl_xor(acc.x, msk, 64);
            acc.y += __shfl_xor(acc.y, msk, 64);
            acc.z += __shfl_xor(acc.z, msk, 64);
            acc.w += __shfl_xor(acc.w, msk, 64);
        }

        if (lane < 16) {
            const float inv = 1.f / (float)npx;
            float4 mean = make_float4(acc.x * inv, acc.y * inv,
                                      acc.z * inv, acc.w * inv);
            const int oidx = anchor_mode ? (y0 * GW + x0) * 16 + lane
                                         : cell * 16 + lane;
            dst[oidx] = mean;
        }

        if (!have_next) break;
        cell = ncell;
        y0 = ny0; y1 = ny1; x0 = nx0; x1 = nx1;   // consume prefetched descs
    }
}

// Dense streaming broadcast, means from ws. NONTEMPORAL out stores (147 MB
// write-once; skip L2 write-allocate). Unroll 6 -> 6 independent means-load
// chains in flight. Grid MUST be 2048x256: 768*768*16 / (2048*256) = 18/thread.
__global__ __launch_bounds__(256) void bcast_ws(float4* __restrict__ out,
                                                const float4* __restrict__ means,
                                                const int* __restrict__ ws) {
    const int ncols = ws[OFF_NCOLS];
    int g = blockIdx.x * 256 + threadIdx.x;
    #pragma unroll 6
    for (int it = 0; it < 18; ++it, g += 2048 * 256) {
        const int p  = g >> 4;
        const int cq = g & 15;
        const int y  = p / GW;              // constant divisor -> magic mul
        const int x  = p - y * GW;
        const int rid = ws[OFF_ROWID + y];
        const int cid = ws[OFF_COLID + x];
        const float4 v = means[(rid * ncols + cid) * 16 + cq];
        __builtin_nontemporal_store(*(const f32x4*)&v, (f32x4*)&out[g]);
    }
}

// Fallback broadcast: means live at each cell's anchor pixel inside out.
// Reads/writes alias through `out` (conservative ordering) — correct, slower.
__global__ __launch_bounds__(256) void bcast_anchor(float4* out,
                                                    const int* __restrict__ ws) {
    int g = blockIdx.x * 256 + threadIdx.x;
    for (int it = 0; it < 18; ++it, g += 2048 * 256) {
        const int p  = g >> 4;
        const int cq = g & 15;
        const int y  = p / GW;
        const int x  = p - y * GW;
        const int rid = ws[OFF_ROWID + y];
        const int cid = ws[OFF_COLID + x];
        const int ya  = ws[OFF_ROWSTART + rid];
        const int xa  = ws[OFF_COLSTART + cid];
        out[g] = out[(ya * GW + xa) * 16 + cq];   // anchor holds the mean
    }
}

extern "C" void kernel_launch(void* const* d_in, const int* in_sizes, int n_in,
                              void* d_out, int out_size, void* d_ws, size_t ws_size,
                              hipStream_t stream) {
    const float* in  = (const float*)d_in[0];   // [1,768,768,64] fp32
    const int* hmask = (const int*)d_in[1];     // [1,768] int32
    const int* vmask = (const int*)d_in[2];     // [1,768] int32
    float* out = (float*)d_out;                 // [1,768,768,64] fp32
    int* ws = (int*)d_ws;

    seg_scan<<<2, GH, 0, stream>>>(hmask, vmask, ws);

    // means buffer: worst case MAXSEG*MAXSEG cells x 64 ch x 4 B
    const size_t need = (size_t)OFF_MEANS * 4
                      + (size_t)MAXSEG * MAXSEG * 64 * 4;
    if (ws_size >= need) {
        float4* means = (float4*)(ws + OFF_MEANS);
        cell_mean3<<<2048, 256, 0, stream>>>((const float4*)in, means, ws, 0);
        bcast_ws<<<2048, 256, 0, stream>>>((float4*)out, means, ws);
    } else {
        cell_mean3<<<2048, 256, 0, stream>>>((const float4*)in, (float4*)out, ws, 1);
        bcast_anchor<<<2048, 256, 0, stream>>>((float4*)out, ws);
    }
}